// Round 11
// baseline (1336.140 us; speedup 1.0000x reference)
//
#include <hip/hip_runtime.h>
#include <math.h>

#define NTOK 65536
#define DIMD 128
#define KCB  2048
#define CAP  16

typedef unsigned short u16;
typedef __attribute__((ext_vector_type(8))) unsigned short u16x8;
typedef __attribute__((ext_vector_type(8))) __bf16 bf16x8;
typedef __attribute__((ext_vector_type(4))) float f32x4;

union U8 { u16x8 u; bf16x8 b; };

__device__ __forceinline__ u16 f2bf(float f) {
  union { float f; unsigned u; } c; c.f = f;
  unsigned r = c.u + 0x7FFFu + ((c.u >> 16) & 1u);
  return (u16)(r >> 16);
}
__device__ __forceinline__ float bf2f(u16 h) {
  union { unsigned u; float f; } c; c.u = ((unsigned)h) << 16;
  return c.f;
}

__device__ __forceinline__ float block_reduce4(float v, volatile float* sm, int tid) {
  #pragma unroll
  for (int off = 32; off; off >>= 1) v += __shfl_xor(v, off, 64);
  __syncthreads();
  if ((tid & 63) == 0) sm[tid >> 6] = v;
  __syncthreads();
  float r = sm[0] + sm[1] + sm[2] + sm[3];
  __syncthreads();
  return r;
}

// linear tile staging: thread tid covers bytes [tid*16 + i*4096]; dest mirrors source
__device__ __forceinline__ void stage8(const char* srcLane, char* ldsWaveBase) {
  #pragma unroll
  for (int i = 0; i < 8; ++i)
    __builtin_amdgcn_global_load_lds((const __attribute__((address_space(1))) void*)(srcLane + i * 4096),
                                     (__attribute__((address_space(3))) void*)(ldsWaveBase + i * 4096), 16, 0, 0);
}

// ---------------- small kernels ----------------

__global__ __launch_bounds__(256) void k_zero(float* __restrict__ avgp, float* __restrict__ t1,
                                              float* __restrict__ acc3, float* __restrict__ cnt,
                                              int* __restrict__ cndCnt) {
  const int i = blockIdx.x * 256 + threadIdx.x;
  if (i < KCB) { avgp[i] = 0.0f; cnt[i] = 0.0f; }
  if (i < NTOK) cndCnt[i] = 0;
  if (i == 0) { t1[0] = 0.0f; acc3[0] = 0.0f; acc3[1] = 0.0f; acc3[2] = 0.0f; }
}

// normalize rows of x -> bf16 split halves (one wave per row)
__global__ __launch_bounds__(256) void k_prepx(const float* __restrict__ x, const float* __restrict__ mask,
                                               u16* __restrict__ xh, u16* __restrict__ xl) {
  const int wid = (blockIdx.x * 256 + threadIdx.x) >> 6;
  const int lane = threadIdx.x & 63;
  if (wid >= NTOK) return;
  const float add = (1.0f - mask[wid]) * 1e-6f;
  const float2 v = *(const float2*)(x + (size_t)wid * DIMD + lane * 2);
  const float a0 = v.x + add, a1 = v.y + add;
  float ss = a0 * a0 + a1 * a1;
  #pragma unroll
  for (int off = 32; off; off >>= 1) ss += __shfl_xor(ss, off, 64);
  const float sc = 1.0f / fmaxf(sqrtf(ss), 1e-6f);
  const float f0 = a0 * sc, f1 = a1 * sc;
  const u16 h0 = f2bf(f0), h1 = f2bf(f1);
  const u16 g0 = f2bf(f0 - bf2f(h0)), g1 = f2bf(f1 - bf2f(h1));
  union { u16 s[2]; unsigned u; } wh, wl;
  wh.s[0] = h0; wh.s[1] = h1; wl.s[0] = g0; wl.s[1] = g1;
  *(unsigned*)(xh + (size_t)wid * DIMD + lane * 2) = wh.u;
  *(unsigned*)(xl + (size_t)wid * DIMD + lane * 2) = wl.u;
}

// pack codebook to bf16 H+L in MFMA-fragment order, 64-code tiles (R8 layout):
// tile T in [0,32): bytes [T*32768, +16384) = H frags, [+16384, +32768) = L frags
// frag f = ks*4+nf in [0,16): 64 lanes x 16B; code c = T*64+nf*16+(lane&15), dims d = ks*32+(lane>>4)*8..+8
__global__ __launch_bounds__(256) void k_packcb(const float* __restrict__ cb, u16* __restrict__ cbp) {
  const int gid = blockIdx.x * 256 + threadIdx.x;
  if (gid >= 32768) return;
  const int lane = gid & 63;
  const int f = (gid >> 6) & 15;
  const int T = gid >> 10;
  const int ks = f >> 2, nf = f & 3;
  const int hi = lane >> 4, l15 = lane & 15;
  const int c = T * 64 + nf * 16 + l15;
  const int d0 = ks * 32 + hi * 8;
  const float4 v0 = *(const float4*)(cb + (size_t)c * DIMD + d0);
  const float4 v1 = *(const float4*)(cb + (size_t)c * DIMD + d0 + 4);
  const float e[8] = {v0.x, v0.y, v0.z, v0.w, v1.x, v1.y, v1.z, v1.w};
  union { u16 s[8]; u16x8 u; } oh, ol;
  #pragma unroll
  for (int i = 0; i < 8; ++i) {
    const u16 h = f2bf(e[i]);
    oh.s[i] = h;
    ol.s[i] = f2bf(e[i] - bf2f(h));
  }
  u16* tile = cbp + (size_t)T * 16384;
  *(u16x8*)(tile + (f * 64 + lane) * 8) = oh.u;
  *(u16x8*)(tile + 8192 + (f * 64 + lane) * 8) = ol.u;
}

__global__ __launch_bounds__(256) void k_gather(const float* __restrict__ cb, const float* __restrict__ mask,
                                                const int* __restrict__ rowIdx, float* __restrict__ outQ,
                                                float* __restrict__ outCnt, float* __restrict__ outEnc) {
  const int g = blockIdx.x * 256 + threadIdx.x;
  const int row = g >> 5, l = g & 31;
  if (row >= NTOK) return;
  const int idx = rowIdx[row];
  const float4 v = *(const float4*)(cb + (size_t)idx * DIMD + l * 4);
  *(float4*)(outQ + (size_t)row * DIMD + l * 4) = v;
  if (l == 0) {
    atomicAdd(&outCnt[idx], mask[row]);
    outEnc[row] = (float)idx;
  }
}

// ---------------- MFMA pass 1 (split precision): per-row max / argmax / candidate lists ----------------

__global__ __launch_bounds__(256, 2) void k_pass1(const u16* __restrict__ xh, const u16* __restrict__ xl,
                                                  const u16* __restrict__ cbp,
                                                  float* __restrict__ rowV1, int* __restrict__ rowIdx,
                                                  int* __restrict__ cndCnt, float2* __restrict__ cands) {
  __shared__ __align__(16) char Bsmem[65536];  // 2 x (16KB H + 16KB L)
  const int tid = threadIdx.x;
  const int lane = tid & 63, w = tid >> 6;
  const int l15 = lane & 15, hi = lane >> 4;
  const int row0 = blockIdx.x * 128;
  const char* src = (const char*)cbp;

  U8 Ah[2][4], Al[2][4];
  #pragma unroll
  for (int mf = 0; mf < 2; ++mf) {
    const size_t arow = (size_t)(row0 + w * 32 + mf * 16 + l15);
    #pragma unroll
    for (int ks = 0; ks < 4; ++ks) {
      Ah[mf][ks].u = *(const u16x8*)(xh + arow * DIMD + ks * 32 + hi * 8);
      Al[mf][ks].u = *(const u16x8*)(xl + arow * DIMD + ks * 32 + hi * 8);
    }
  }

  float v1[8];
  int k1[8];
  #pragma unroll
  for (int r = 0; r < 8; ++r) { v1[r] = -1e30f; k1[r] = 0; }

  stage8(src + 0 * 32768 + tid * 16, Bsmem + 0 * 32768 + w * 1024);
  stage8(src + 1 * 32768 + tid * 16, Bsmem + 1 * 32768 + w * 1024);

  for (int t = 0; t < 32; ++t) {
    const int b = t & 1;
    if (t < 30) asm volatile("s_waitcnt vmcnt(8)" ::: "memory");
    else        asm volatile("s_waitcnt vmcnt(0)" ::: "memory");
    __builtin_amdgcn_sched_barrier(0);
    __builtin_amdgcn_s_barrier();
    __builtin_amdgcn_sched_barrier(0);

    const char* base = Bsmem + b * 32768 + lane * 16;
    f32x4 acc[2][4];
    #pragma unroll
    for (int m = 0; m < 2; ++m)
      #pragma unroll
      for (int nf = 0; nf < 4; ++nf) acc[m][nf] = (f32x4){0.f, 0.f, 0.f, 0.f};

    __builtin_amdgcn_s_setprio(1);
    #pragma unroll
    for (int ks = 0; ks < 4; ++ks) {
      #pragma unroll
      for (int nf = 0; nf < 4; ++nf) {
        U8 bh, bl;
        bh.u = *(const u16x8*)(base + ((ks * 4 + nf) << 10));
        bl.u = *(const u16x8*)(base + 16384 + ((ks * 4 + nf) << 10));
        acc[0][nf] = __builtin_amdgcn_mfma_f32_16x16x32_bf16(Ah[0][ks].b, bh.b, acc[0][nf], 0, 0, 0);
        acc[1][nf] = __builtin_amdgcn_mfma_f32_16x16x32_bf16(Ah[1][ks].b, bh.b, acc[1][nf], 0, 0, 0);
        acc[0][nf] = __builtin_amdgcn_mfma_f32_16x16x32_bf16(Al[0][ks].b, bh.b, acc[0][nf], 0, 0, 0);
        acc[1][nf] = __builtin_amdgcn_mfma_f32_16x16x32_bf16(Al[1][ks].b, bh.b, acc[1][nf], 0, 0, 0);
        acc[0][nf] = __builtin_amdgcn_mfma_f32_16x16x32_bf16(Ah[0][ks].b, bl.b, acc[0][nf], 0, 0, 0);
        acc[1][nf] = __builtin_amdgcn_mfma_f32_16x16x32_bf16(Ah[1][ks].b, bl.b, acc[1][nf], 0, 0, 0);
      }
    }
    __builtin_amdgcn_s_setprio(0);
    asm volatile("s_waitcnt lgkmcnt(0)" ::: "memory");
    __builtin_amdgcn_sched_barrier(0);
    __builtin_amdgcn_s_barrier();
    __builtin_amdgcn_sched_barrier(0);
    if (t < 30)
      stage8(src + (size_t)(t + 2) * 32768 + tid * 16, Bsmem + b * 32768 + w * 1024);

    // epilogue: per-tile merged running max/argmax + candidate append (overlaps prefetch)
    const int colbase = t * 64 + l15;
    #pragma unroll
    for (int m = 0; m < 2; ++m)
      #pragma unroll
      for (int rg = 0; rg < 4; ++rg) {
        const int r = m * 4 + rg;
        float vv = v1[r];
        int kk = k1[r];
        #pragma unroll
        for (int nf = 0; nf < 4; ++nf) {
          const float xv = acc[m][nf][rg];
          if (xv > vv) { vv = xv; kk = colbase + nf * 16; }
        }
        // merge across the 16-lane column group (lanes with same hi share this row)
        #pragma unroll
        for (int off = 1; off <= 8; off <<= 1) {
          const float ov = __shfl_xor(vv, off, 64);
          const int ok = __shfl_xor(kk, off, 64);
          const bool take = (ov > vv) || (ov == vv && ok < kk);
          vv = take ? ov : vv;
          kk = take ? ok : kk;
        }
        v1[r] = vv; k1[r] = kk;
        // candidates: within 0.055 of the (merged) running max => exp weight >= e^-11
        const float thr = vv - 0.055f;
        const bool p0 = acc[m][0][rg] > thr;
        const bool p1 = acc[m][1][rg] > thr;
        const bool p2 = acc[m][2][rg] > thr;
        const bool p3 = acc[m][3][rg] > thr;
        if (__any(p0 | p1 | p2 | p3)) {
          const int row = row0 + w * 32 + m * 16 + hi * 4 + rg;
          #pragma unroll
          for (int nf = 0; nf < 4; ++nf) {
            const float xv = acc[m][nf][rg];
            if (xv > thr) {
              const int slot = atomicAdd(&cndCnt[row], 1);
              if (slot < CAP)
                cands[(size_t)row * CAP + slot] = make_float2(xv, (float)(colbase + nf * 16));
            }
          }
        }
      }
  }

  // final write (v1/k1 already uniform across each 16-lane group)
  #pragma unroll
  for (int m = 0; m < 2; ++m)
    #pragma unroll
    for (int rg = 0; rg < 4; ++rg) {
      const int r = m * 4 + rg;
      if (l15 == 0) {
        const int row = row0 + w * 32 + m * 16 + hi * 4 + rg;
        rowV1[row] = v1[r];
        rowIdx[row] = k1[r];
      }
    }
}

// ---------------- candidate scatter: Z, avg_probs, sample-entropy (one wave per row) ----------------

__global__ __launch_bounds__(256) void k_scatter(const float* __restrict__ mask, const float* __restrict__ rowV1,
                                                 const int* __restrict__ cndCnt, const float2* __restrict__ cands,
                                                 float* __restrict__ avgp, float* __restrict__ t1g) {
  const int wid = (blockIdx.x * 256 + threadIdx.x) >> 6;
  const int lane = threadIdx.x & 63;
  if (wid >= NTOK) return;
  const int cnt = min(cndCnt[wid], CAP);
  const float m = rowV1[wid];
  const float mk = mask[wid];
  float q = 0.f, qd = 0.f;
  int kidx = 0;
  if (lane < cnt) {
    const float2 c = cands[(size_t)wid * CAP + lane];
    const float d = 200.f * (c.x - m);  // <= 0
    q = __expf(d);
    qd = q * d;
    kidx = (int)c.y;
  }
  float Z = q, S = qd;
  #pragma unroll
  for (int off = 32; off; off >>= 1) {
    Z += __shfl_xor(Z, off, 64);
    S += __shfl_xor(S, off, 64);
  }
  if (lane < cnt) atomicAdd(&avgp[kidx], mk * q / Z);
  if (lane == 0 && cnt > 0) atomicAdd(t1g, mk * (__logf(Z) - S / Z));  // mask * per-row entropy
}

// ---------------- scalar reductions ----------------

__global__ __launch_bounds__(256) void k_stats(const float* __restrict__ mask, const float* __restrict__ rowV1,
                                               float* __restrict__ acc3) {
  __shared__ float sm[4];
  const int tid = threadIdx.x;
  float msum = 0.f, slat = 0.f;
  for (int n = blockIdx.x * 256 + tid; n < NTOK; n += gridDim.x * 256) {
    const float mk = mask[n];
    msum += mk;
    slat = fmaf(mk, 2.0f - 2.0f * rowV1[n], slat);
  }
  msum = block_reduce4(msum, sm, tid);
  slat = block_reduce4(slat, sm, tid);
  if (tid == 0) {
    atomicAdd(&acc3[0], msum);
    atomicAdd(&acc3[1], slat);
  }
}

__global__ __launch_bounds__(256) void k_final(const float* __restrict__ avgp, const float* __restrict__ t1g,
                                               const float* __restrict__ acc3, float* __restrict__ out3) {
  __shared__ float sm[4];
  const int tid = threadIdx.x;
  const float msum = acc3[0];
  float ae = 0.f;
  for (int k2 = tid; k2 < KCB; k2 += 256) {
    const float a = avgp[k2] / msum;
    ae += a * __logf(a + 1e-5f);
  }
  ae = block_reduce4(ae, sm, tid);
  if (tid == 0) {
    const float sample_entropy = t1g[0] / msum;  // t1g = sum mask * (-sum p log p)
    const float lat = acc3[1] / (msum + 1e-6f);
    out3[0] = lat;
    out3[1] = lat;
    out3[2] = sample_entropy + ae;  // ae = -avg_entropy
  }
}

// ---------------- launcher ----------------

extern "C" void kernel_launch(void* const* d_in, const int* in_sizes, int n_in,
                              void* d_out, int out_size, void* d_ws, size_t ws_size,
                              hipStream_t stream) {
  const float* x = (const float*)d_in[0];
  const float* mask = (const float*)d_in[1];
  const float* cb = (const float*)d_in[2];

  float* out = (float*)d_out;
  float* outQ = out;
  float* out3 = out + (size_t)NTOK * DIMD;
  float* outCnt = out3 + 3;
  float* outEnc = outCnt + KCB;

  // bf16-split x lives in the quantized output region until k_gather overwrites it
  u16* xh = (u16*)outQ;
  u16* xl = xh + (size_t)NTOK * DIMD;

  float* ws = (float*)d_ws;
  float* rowV1 = ws;                             // N
  int* rowIdx = (int*)(ws + (size_t)NTOK);       // N
  float* avgp = ws + 2 * (size_t)NTOK;           // K
  float* t1g = avgp + KCB;                       // 1
  float* acc3 = t1g + 1;                         // 3
  int* cndCnt = (int*)(acc3 + 5);                // N
  float2* cands = (float2*)(cndCnt + NTOK);      // N*CAP float2 (8 MB)
  u16* cbp = (u16*)(cands + (size_t)NTOK * CAP); // K*D*2 u16 fragment-packed H+L (1 MB)

  k_zero<<<NTOK / 256, 256, 0, stream>>>(avgp, t1g, acc3, outCnt, cndCnt);
  k_prepx<<<(NTOK * 64) / 256, 256, 0, stream>>>(x, mask, xh, xl);
  k_packcb<<<32768 / 256, 256, 0, stream>>>(cb, cbp);
  k_pass1<<<NTOK / 128, 256, 0, stream>>>(xh, xl, cbp, rowV1, rowIdx, cndCnt, cands);
  k_scatter<<<(NTOK * 64) / 256, 256, 0, stream>>>(mask, rowV1, cndCnt, cands, avgp, t1g);
  k_stats<<<64, 256, 0, stream>>>(mask, rowV1, acc3);
  // gather runs after pass1 (outQ aliases xh/xl; pass1 is their last reader)
  k_gather<<<(NTOK * 32) / 256, 256, 0, stream>>>(cb, mask, rowIdx, outQ, outCnt, outEnc);
  k_final<<<1, 256, 0, stream>>>(avgp, t1g, acc3, out3);
}